// Round 9
// baseline (295.484 us; speedup 1.0000x reference)
//
#include <hip/hip_runtime.h>
#include <hip/hip_bf16.h>

// ---------------------------------------------------------------------------
// myGRUCell low-rank, R9: k1 rewritten m97-style (block-cooperative coalesced
// staging, 32KB LDS, 2 barriers/chunk, 16 waves/CU).  k23/k4 unchanged (R8).
// ws layout (shorts): Wt[64][1024] | Ut | P1t[1024][128] | P2t | P3t |
//                     A12[32768][128] | rhU[32768][64]
// ---------------------------------------------------------------------------

typedef __attribute__((ext_vector_type(8))) short short8;
typedef __attribute__((ext_vector_type(4))) float f32x4;
typedef __attribute__((ext_vector_type(4))) float f4;
typedef __attribute__((ext_vector_type(2))) unsigned int uint2v;

#define WS_UT   65536
#define WS_P1T  131072
#define WS_P2T  262144
#define WS_P3T  393216
#define WS_A12  524288
#define WS_RHU  4718592

__device__ __forceinline__ short f2bf(float f) {
  unsigned u = __builtin_bit_cast(unsigned, f);
  u += 0x7FFFu + ((u >> 16) & 1u);          // round-nearest-even
  return (short)(u >> 16);
}
__device__ __forceinline__ unsigned pack2(float a, float b) {
  return (unsigned)(unsigned short)f2bf(a) | ((unsigned)(unsigned short)f2bf(b) << 16);
}
__device__ __forceinline__ short8 cvt8(f4 a, f4 b) {
  short8 r;
#pragma unroll
  for (int j = 0; j < 4; ++j) { r[j] = f2bf(a[j]); r[4 + j] = f2bf(b[j]); }
  return r;
}
__device__ __forceinline__ f32x4 mfma16(short8 a, short8 b, f32x4 c) {
  return __builtin_amdgcn_mfma_f32_16x16x32_bf16(a, b, c, 0, 0, 0);
}
__device__ __forceinline__ short8 ldg8(const short* p) {
  return *reinterpret_cast<const short8*>(p);
}
__device__ __forceinline__ f4 ldf4(const float* p) {
  return *reinterpret_cast<const f4*>(p);
}

// async 16B global->LDS (k23/k4)
__device__ __forceinline__ void cp16(void* l, const void* g) {
  __builtin_amdgcn_global_load_lds(
      (const __attribute__((address_space(1))) void*)g,
      (__attribute__((address_space(3))) void*)l, 16, 0, 0);
}
#define VWAIT(N) do { asm volatile("s_waitcnt vmcnt(" #N ")" ::: "memory"); \
                      __builtin_amdgcn_sched_barrier(0); } while (0)

// [R][128]-short LDS tile, XOR-swizzled 16B granules
__device__ __forceinline__ short8 rd128s(const short* b, int row, int col) {
  return *reinterpret_cast<const short8*>(b + row * 128 + (col ^ ((row & 7) << 3)));
}
__device__ __forceinline__ void wr128s(short* b, int row, int col8, short8 v) {
  *reinterpret_cast<short8*>(b + row * 128 + (col8 ^ ((row & 7) << 3))) = v;
}
// [16][64]-short per-wave transpose buffer
__device__ __forceinline__ void wr64(short* b, int row, int col, short v) {
  b[row * 64 + (col ^ ((row & 7) << 3))] = v;
}
__device__ __forceinline__ short8 rd64(const short* b, int row, int col) {
  return *reinterpret_cast<const short8*>(b + row * 64 + (col ^ ((row & 7) << 3)));
}

#define LOG2E 1.4426950408889634f
__device__ __forceinline__ float sigm_f(float v) {
  return __builtin_amdgcn_rcpf(1.f + __builtin_amdgcn_exp2f(-v * LOG2E));
}
__device__ __forceinline__ float tanh_f(float v) {
  float t = __builtin_amdgcn_exp2f(v * (2.f * LOG2E));
  return 1.f - 2.f * __builtin_amdgcn_rcpf(t + 1.f);
}

// ---------------------------------------------------------------------------
__global__ void prep_kernel(const float* __restrict__ W,  const float* __restrict__ W1,
                            const float* __restrict__ W2, const float* __restrict__ W3,
                            const float* __restrict__ U,  const float* __restrict__ U1,
                            const float* __restrict__ U2, const float* __restrict__ U3,
                            short* __restrict__ ws) {
  int i = blockIdx.x * blockDim.x + threadIdx.x;
  float v;
  if (i < 65536) {
    int n = i >> 10, k = i & 1023;
    v = W[k * 64 + n];
  } else if (i < 131072) {
    int j = i - 65536;
    int n = j >> 10, k = j & 1023;
    v = U[k * 64 + n];
  } else {
    int j = i - 131072;
    int sel = j >> 17;
    int jj = j & 131071;
    int n = jj >> 7, k = jj & 127;
    const float* Wk = sel == 0 ? W1 : sel == 1 ? W2 : W3;
    const float* Uk = sel == 0 ? U1 : sel == 1 ? U2 : U3;
    v = (k < 64) ? Wk[k * 1024 + n] : Uk[(k - 64) * 1024 + n];
  }
  ws[i] = f2bf(v);
}

// ---------------------------------------------------------------------------
// k1 (R9): A12 = [x@W | h@U].  Block = 64 rows, 4 waves, 8 K-chunks of 128.
// Cooperative coalesced staging (512B per 32-lane group) f32->bf16 -> LDS,
// barrier, per-wave MFMA strip, barrier.  grid 512.
// ---------------------------------------------------------------------------
__global__ __launch_bounds__(256, 4) void k1_a12(
    const float* __restrict__ x, const float* __restrict__ h,
    const short* __restrict__ ws, short* __restrict__ A12) {
  __shared__ __align__(16) short sX[64 * 128];   // 16 KB
  __shared__ __align__(16) short sH[64 * 128];   // 16 KB

  const int tid = threadIdx.x;
  const int w = tid >> 6, l = tid & 63, l15 = l & 15, lg = l >> 4;
  const int r0 = blockIdx.x * 64;
  const short* Wt = ws;
  const short* Ut = ws + WS_UT;

  const int strow = tid >> 5;        // 0..7 row subgroup
  const int sc4   = tid & 31;        // f4-column within 128-f32 chunk

  f32x4 accX[4] = {}, accH[4] = {};

#pragma unroll 1
  for (int c = 0; c < 8; ++c) {
    // ---- cooperative stage: x and h [64 rows][128 cols] -> bf16 LDS
    {
      f4 xv[8], hv[8];
#pragma unroll
      for (int i = 0; i < 8; ++i) {
        const int row = i * 8 + strow;
        xv[i] = ldf4(x + (size_t)(r0 + row) * 1024 + c * 128 + sc4 * 4);
        hv[i] = ldf4(h + (size_t)(r0 + row) * 1024 + c * 128 + sc4 * 4);
      }
#pragma unroll
      for (int i = 0; i < 8; ++i) {
        const int row = i * 8 + strow;
        const int off = row * 128 + ((sc4 * 4) ^ ((row & 7) << 3));
        uint2v px, ph;
        px.x = pack2(xv[i][0], xv[i][1]); px.y = pack2(xv[i][2], xv[i][3]);
        ph.x = pack2(hv[i][0], hv[i][1]); ph.y = pack2(hv[i][2], hv[i][3]);
        *reinterpret_cast<uint2v*>(&sX[off]) = px;
        *reinterpret_cast<uint2v*>(&sH[off]) = ph;
      }
    }
    __syncthreads();

    // ---- per-wave compute: rows 16w..16w+15, all 128 output cols
#pragma unroll
    for (int ks = 0; ks < 4; ++ks) {
      short8 ax = rd128s(sX, 16 * w + l15, ks * 32 + lg * 8);
      short8 ah = rd128s(sH, 16 * w + l15, ks * 32 + lg * 8);
#pragma unroll
      for (int cf = 0; cf < 4; ++cf) {
        short8 bw = ldg8(Wt + (size_t)(cf * 16 + l15) * 1024 + c * 128 + ks * 32 + lg * 8);
        accX[cf] = mfma16(ax, bw, accX[cf]);
      }
#pragma unroll
      for (int cf = 0; cf < 4; ++cf) {
        short8 bu = ldg8(Ut + (size_t)(cf * 16 + l15) * 1024 + c * 128 + ks * 32 + lg * 8);
        accH[cf] = mfma16(ah, bu, accH[cf]);
      }
    }
    __syncthreads();
  }

  // ---- store: C row' = lg*4+j within strip
#pragma unroll
  for (int cf = 0; cf < 4; ++cf)
#pragma unroll
    for (int j = 0; j < 4; ++j) {
      const size_t rr = (size_t)(r0 + 16 * w + lg * 4 + j) * 128;
      A12[rr + cf * 16 + l15]      = f2bf(accX[cf][j]);
      A12[rr + 64 + cf * 16 + l15] = f2bf(accH[cf][j]);
    }
}

// ---------------------------------------------------------------------------
// k23 (R8, unchanged): rhU = (sigmoid(A12@P1 + h*U1d + bR) * h) @ U.
// ---------------------------------------------------------------------------
__global__ __launch_bounds__(256, 2) void k23_rhu(
    const float* __restrict__ h, const float* __restrict__ u1d,
    const float* __restrict__ biasR,
    const short* __restrict__ ws, const short* __restrict__ A12,
    short* __restrict__ rhU) {
  const short* Ut  = ws + WS_UT;
  const short* P1t = ws + WS_P1T;
  __shared__ __align__(16) float hS[2][4][16 * 64];
  __shared__ __align__(16) short sT[4][16 * 64];

  const int tid = threadIdx.x;
  const int w = tid >> 6, l = tid & 63, l15 = l & 15, lg = l >> 4;
  const int sr = blockIdx.x * 64 + w * 16;

  const int srow = l >> 4;
  const int slin = (l & 15) * 16;

  auto STAGE = [&](int t, int b) {
#pragma unroll
    for (int i = 0; i < 4; ++i) {
      int r = i * 4 + srow;
      int kb = slin ^ ((r & 7) << 4);
      cp16((char*)&hS[b][w][0] + i * 1024,
           (const char*)(h + (size_t)(sr + r) * 1024 + t * 64) + kb);
    }
  };

  short8 a12[4];
#pragma unroll
  for (int k0 = 0; k0 < 4; ++k0)
    a12[k0] = ldg8(A12 + (size_t)(sr + l15) * 128 + k0 * 32 + lg * 8);

  f32x4 accU[4] = {};
  STAGE(0, 0);
#pragma unroll 1
  for (int tt = 0; tt < 16; ++tt) {
    const int n0 = tt * 64;
    short8 b1[4][4], bu[2][4];
    float d1_[4], br_[4];
#pragma unroll
    for (int ks = 0; ks < 4; ++ks)
#pragma unroll
      for (int cf = 0; cf < 4; ++cf)
        b1[ks][cf] = ldg8(P1t + (size_t)(n0 + cf * 16 + l15) * 128 + ks * 32 + lg * 8);
#pragma unroll
    for (int kk = 0; kk < 2; ++kk)
#pragma unroll
      for (int cf = 0; cf < 4; ++cf)
        bu[kk][cf] = ldg8(Ut + (size_t)(cf * 16 + l15) * 1024 + n0 + kk * 32 + lg * 8);
#pragma unroll
    for (int cf = 0; cf < 4; ++cf) {
      d1_[cf] = u1d[n0 + cf * 16 + l15];
      br_[cf] = biasR[n0 + cf * 16 + l15];
    }
    if (tt < 15) { STAGE(tt + 1, (tt + 1) & 1); VWAIT(4); }
    else         { VWAIT(0); }
    const char* H = (const char*)&hS[tt & 1][w][0];

    float hv[4][4];
#pragma unroll
    for (int cf = 0; cf < 4; ++cf)
#pragma unroll
      for (int j = 0; j < 4; ++j) {
        int rr = lg * 4 + j;
        hv[cf][j] = *(const float*)(H + rr * 256 + ((cf * 64 + l15 * 4) ^ ((rr & 7) << 4)));
      }
    f32x4 accR[4] = {};
#pragma unroll
    for (int ks = 0; ks < 4; ++ks)
#pragma unroll
      for (int cf = 0; cf < 4; ++cf) accR[cf] = mfma16(a12[ks], b1[ks][cf], accR[cf]);
#pragma unroll
    for (int cf = 0; cf < 4; ++cf)
#pragma unroll
      for (int j = 0; j < 4; ++j) {
        float rv = sigm_f(accR[cf][j] + hv[cf][j] * d1_[cf] + br_[cf]);
        wr64(&sT[w][0], lg * 4 + j, cf * 16 + l15, f2bf(rv * hv[cf][j]));
      }
    short8 arh0 = rd64(&sT[w][0], l15, lg * 8);
    short8 arh1 = rd64(&sT[w][0], l15, 32 + lg * 8);
#pragma unroll
    for (int cf = 0; cf < 4; ++cf) accU[cf] = mfma16(arh0, bu[0][cf], accU[cf]);
#pragma unroll
    for (int cf = 0; cf < 4; ++cf) accU[cf] = mfma16(arh1, bu[1][cf], accU[cf]);
  }
#pragma unroll
  for (int cf = 0; cf < 4; ++cf)
#pragma unroll
    for (int j = 0; j < 4; ++j)
      rhU[(size_t)(sr + lg * 4 + j) * 64 + cf * 16 + l15] = f2bf(accU[cf][j]);
}

// ---------------------------------------------------------------------------
// k4 (R8, unchanged): out = z*h + (1-z)*tanh(pre_c).
// ---------------------------------------------------------------------------
__global__ __launch_bounds__(256, 2) void k4_out(
    const float* __restrict__ h,
    const float* __restrict__ u1d, const float* __restrict__ u2d,
    const float* __restrict__ u3d,
    const float* __restrict__ biasR, const float* __restrict__ biasZ,
    const float* __restrict__ biasU,
    const short* __restrict__ ws, const short* __restrict__ A12,
    const short* __restrict__ rhU, float* __restrict__ out) {
  __shared__ __align__(16) short sB1[64 * 128], sB2[64 * 128], sB3[64 * 128];
  __shared__ __align__(16) float hS[2][4][16 * 64];

  const int tid = threadIdx.x;
  const int w = tid >> 6, l = tid & 63, l15 = l & 15, lg = l >> 4;
  const int ct = blockIdx.x & 15, rc = blockIdx.x >> 4;
  const int n0 = ct * 64;

#pragma unroll
  for (int mat = 0; mat < 3; ++mat) {
    const short* srcw = (mat == 0) ? (ws + WS_P1T) : (mat == 1) ? (ws + WS_P2T) : (ws + WS_P3T);
    short* dst = (mat == 0) ? sB1 : (mat == 1) ? sB2 : sB3;
#pragma unroll
    for (int i = 0; i < 4; ++i) {
      int id = tid + i * 256;
      int row = id >> 4, gc = id & 15;
      wr128s(dst, row, gc * 8, ldg8(srcw + (size_t)(n0 + row) * 128 + gc * 8));
    }
  }
  float d1_[4], d2_[4], d3_[4], br_[4], bz_[4], bu_[4];
#pragma unroll
  for (int cf = 0; cf < 4; ++cf) {
    const int cc = n0 + cf * 16 + l15;
    d1_[cf] = u1d[cc]; d2_[cf] = u2d[cc]; d3_[cf] = u3d[cc];
    br_[cf] = biasR[cc]; bz_[cf] = biasZ[cc]; bu_[cf] = biasU[cc];
  }
  __syncthreads();

  const int srow = l >> 4;
  const int slin = (l & 15) * 16;
  auto STAGE = [&](int rnd, int b) {
    const int sb = rc * 512 + rnd * 64 + w * 16;
#pragma unroll
    for (int i = 0; i < 4; ++i) {
      int r = i * 4 + srow;
      int kb = slin ^ ((r & 7) << 4);
      cp16((char*)&hS[b][w][0] + i * 1024,
           (const char*)(h + (size_t)(sb + r) * 1024 + n0) + kb);
    }
  };

  STAGE(0, 0);
#pragma unroll 1
  for (int rnd = 0; rnd < 8; ++rnd) {
    const int sr = rc * 512 + rnd * 64 + w * 16;
    short8 a12[4], arhu[2];
#pragma unroll
    for (int k0 = 0; k0 < 4; ++k0)
      a12[k0] = ldg8(A12 + (size_t)(sr + l15) * 128 + k0 * 32 + lg * 8);
#pragma unroll
    for (int kk = 0; kk < 2; ++kk)
      arhu[kk] = ldg8(rhU + (size_t)(sr + l15) * 64 + kk * 32 + lg * 8);
    if (rnd < 7) { STAGE(rnd + 1, (rnd + 1) & 1); VWAIT(4); }
    else         { VWAIT(0); }
    const char* H = (const char*)&hS[rnd & 1][w][0];

    float hv[4][4];
#pragma unroll
    for (int cf = 0; cf < 4; ++cf)
#pragma unroll
      for (int j = 0; j < 4; ++j) {
        int rr = lg * 4 + j;
        hv[cf][j] = *(const float*)(H + rr * 256 + ((cf * 64 + l15 * 4) ^ ((rr & 7) << 4)));
      }

    f32x4 aR[4] = {}, aZ[4] = {}, aC[4] = {};
#pragma unroll
    for (int k0 = 0; k0 < 4; ++k0) {
      const short8 a3 = (k0 < 2) ? a12[k0] : arhu[k0 - 2];
#pragma unroll
      for (int cf = 0; cf < 4; ++cf) {
        aR[cf] = mfma16(a12[k0], rd128s(sB1, cf * 16 + l15, k0 * 32 + lg * 8), aR[cf]);
        aZ[cf] = mfma16(a12[k0], rd128s(sB2, cf * 16 + l15, k0 * 32 + lg * 8), aZ[cf]);
        aC[cf] = mfma16(a3,      rd128s(sB3, cf * 16 + l15, k0 * 32 + lg * 8), aC[cf]);
      }
    }
#pragma unroll
    for (int cf = 0; cf < 4; ++cf) {
      const int cc = n0 + cf * 16 + l15;
#pragma unroll
      for (int j = 0; j < 4; ++j) {
        const size_t gi = (size_t)(sr + lg * 4 + j) * 1024 + cc;
        const float hvj = hv[cf][j];
        float rv = sigm_f(aR[cf][j] + hvj * d1_[cf] + br_[cf]);
        float zv = sigm_f(aZ[cf][j] + hvj * d2_[cf] + bz_[cf]);
        float cv = tanh_f(aC[cf][j] + rv * hvj * d3_[cf] + bu_[cf]);
        out[gi] = zv * hvj + (1.f - zv) * cv;
      }
    }
  }
}

extern "C" void kernel_launch(void* const* d_in, const int* in_sizes, int n_in,
                              void* d_out, int out_size, void* d_ws, size_t ws_size,
                              hipStream_t stream) {
  const float* x   = (const float*)d_in[0];
  const float* h   = (const float*)d_in[1];
  const float* W   = (const float*)d_in[2];
  const float* W1  = (const float*)d_in[3];
  const float* W2  = (const float*)d_in[4];
  const float* W3  = (const float*)d_in[5];
  const float* U   = (const float*)d_in[6];
  const float* U1  = (const float*)d_in[7];
  const float* U2  = (const float*)d_in[8];
  const float* U3  = (const float*)d_in[9];
  const float* u1d = (const float*)d_in[10];
  const float* u2d = (const float*)d_in[11];
  const float* u3d = (const float*)d_in[12];
  const float* bR  = (const float*)d_in[13];
  const float* bZ  = (const float*)d_in[14];
  const float* bU  = (const float*)d_in[15];
  short* ws  = (short*)d_ws;
  short* A12 = ws + WS_A12;
  short* rhU = ws + WS_RHU;

  prep_kernel<<<2048, 256, 0, stream>>>(W, W1, W2, W3, U, U1, U2, U3, ws);
  k1_a12<<<512, 256, 0, stream>>>(x, h, ws, A12);
  k23_rhu<<<512, 256, 0, stream>>>(h, u1d, bR, ws, A12, rhU);
  k4_out<<<1024, 256, 0, stream>>>(h, u1d, u2d, u3d, bR, bZ, bU, ws, A12, rhU, (float*)d_out);
}